// Round 7
// baseline (690.442 us; speedup 1.0000x reference)
//
#include <hip/hip_runtime.h>

#define B_ 32
#define P_ 1024
#define V_ 100
#define E_ 512
#define H_ 512
#define C_ 512
#define EPS_ 1e-5f

typedef float f32x4 __attribute__((ext_vector_type(4)));
typedef short bf16x8 __attribute__((ext_vector_type(8)));

#define GLB(p) ((const __attribute__((address_space(1))) unsigned int*)(p))
#define LDSP(p) ((__attribute__((address_space(3))) unsigned int*)(p))

__device__ __forceinline__ unsigned short f2bf(float f) {
  unsigned int u = __float_as_uint(f);
  u += 0x7fffu + ((u >> 16) & 1u);
  return (unsigned short)(u >> 16);
}
__device__ __forceinline__ float bf2f(unsigned short s) {
  return __uint_as_float(((unsigned int)s) << 16);
}

// K0: transpose w1 [H][E*3] -> w1T [E*3][H]
__global__ __launch_bounds__(256) void w1t_kernel(const float* __restrict__ w1,
                                                  float* __restrict__ w1T) {
  __shared__ float tile[64][65];
  int h0 = blockIdx.x * 64;
  int e0 = blockIdx.y * 64;
  int t = threadIdx.x;
  int c = t & 63, r4 = t >> 6;
#pragma unroll
  for (int r = 0; r < 64; r += 4)
    tile[r + r4][c] = w1[(size_t)(h0 + r + r4) * 1536 + e0 + c];
  __syncthreads();
#pragma unroll
  for (int r = 0; r < 64; r += 4)
    w1T[(size_t)(e0 + r + r4) * 512 + h0 + c] = tile[c][r + r4];
}

// K1: G[k][v][h] = scale1[h] * sum_e w1T[3e+k][h] * emb[v,e]
// r4 config (known-good): grid (V, H/64), 64 threads -> ~3 waves/CU everywhere.
__global__ __launch_bounds__(64) void g_kernel(const float* __restrict__ emb,
                                               const float* __restrict__ w1T,
                                               const float* __restrict__ g1,
                                               const float* __restrict__ vr1,
                                               float* __restrict__ G) {
  __shared__ float se[E_];
  int v = blockIdx.x;
  int h = blockIdx.y * 64 + threadIdx.x;
  for (int i = threadIdx.x; i < E_; i += 64) se[i] = emb[(size_t)v * E_ + i];
  __syncthreads();
  float a0 = 0.f, a1 = 0.f, a2 = 0.f;
#pragma unroll 4
  for (int e = 0; e < E_; ++e) {
    float x = se[e];
    const float* wp = w1T + (size_t)(3 * e) * H_ + h;
    a0 = fmaf(wp[0], x, a0);
    a1 = fmaf(wp[H_], x, a1);
    a2 = fmaf(wp[2 * H_], x, a2);
  }
  float sc = g1[h] * rsqrtf(vr1[h] + EPS_);
  G[((size_t)0 * V_ + v) * H_ + h] = a0 * sc;
  G[((size_t)1 * V_ + v) * H_ + h] = a1 * sc;
  G[((size_t)2 * V_ + v) * H_ + h] = a2 * sc;
}

// K1b: repack/split w2 -> A2 (H x 1536, j = k*C + c), fold scale2; biases.
__global__ __launch_bounds__(256) void a2_kernel(
    const float* __restrict__ w2, const float* __restrict__ b1,
    const float* __restrict__ g1, const float* __restrict__ be1,
    const float* __restrict__ mn1, const float* __restrict__ vr1,
    const float* __restrict__ b2, const float* __restrict__ g2,
    const float* __restrict__ be2, const float* __restrict__ mn2,
    const float* __restrict__ vr2, float* __restrict__ bias1,
    float* __restrict__ bias2, unsigned short* __restrict__ A2h,
    unsigned short* __restrict__ A2l) {
  int h = blockIdx.x;
  int tid = threadIdx.x;
  float sc1 = g1[h] * rsqrtf(vr1[h] + EPS_);
  float sc2 = g2[h] * rsqrtf(vr2[h] + EPS_);
  if (tid == 0) {
    bias1[h] = b1[h] * sc1 + be1[h] - mn1[h] * sc1;
    bias2[h] = b2[h] * sc2 + be2[h] - mn2[h] * sc2;
  }
  for (int j = tid; j < 3 * C_; j += 256) {
    int k = j >> 9;
    int c = j & (C_ - 1);
    float val = w2[((size_t)h * C_ + c) * 3 + k] * sc2;
    unsigned short hi = f2bf(val);
    A2h[(size_t)h * (3 * C_) + j] = hi;
    A2l[(size_t)h * (3 * C_) + j] = f2bf(val - bf2f(hi));
  }
}

// K2: h1T[b][r][c] padded rows; 2 channels/thread, packed stores
__global__ __launch_bounds__(256) void embed_conv1_kernel(
    const int* __restrict__ ids, const float* __restrict__ G,
    const float* __restrict__ bias1, unsigned short* __restrict__ Bh,
    unsigned short* __restrict__ Bl) {
  int r = blockIdx.x % (P_ + 2);
  int b = blockIdx.x / (P_ + 2);
  int t = threadIdx.x;
  size_t outbase = ((size_t)b * (P_ + 2) + r) * C_;
  unsigned int* BhU = (unsigned int*)(Bh + outbase);
  unsigned int* BlU = (unsigned int*)(Bl + outbase);
  if (r == 0 || r == P_ + 1) {
    BhU[t] = 0u;
    BlU[t] = 0u;
    return;
  }
  int p = r - 1;
  int v0 = (p >= 1) ? ids[b * P_ + p - 1] : -1;
  int v1 = ids[b * P_ + p];
  int v2 = (p + 1 < P_) ? ids[b * P_ + p + 1] : -1;
  const float2* G0 = (v0 >= 0) ? (const float2*)(G + ((size_t)0 * V_ + v0) * H_) : nullptr;
  const float2* G1 = (const float2*)(G + ((size_t)1 * V_ + v1) * H_);
  const float2* G2 = (v2 >= 0) ? (const float2*)(G + ((size_t)2 * V_ + v2) * H_) : nullptr;
  const float2* bi = (const float2*)bias1;

  float2 s = bi[t];
  float2 gm = G1[t];
  s.x += gm.x;
  s.y += gm.y;
  if (G0) { float2 g0 = G0[t]; s.x += g0.x; s.y += g0.y; }
  if (G2) { float2 g2v = G2[t]; s.x += g2v.x; s.y += g2v.y; }
  s.x = fmaxf(s.x, 0.f);
  s.y = fmaxf(s.y, 0.f);
  unsigned short h0 = f2bf(s.x), h1 = f2bf(s.y);
  unsigned short l0 = f2bf(s.x - bf2f(h0)), l1 = f2bf(s.y - bf2f(h1));
  BhU[t] = (unsigned int)h0 | ((unsigned int)h1 << 16);
  BlU[t] = (unsigned int)l0 | ((unsigned int)l1 << 16);
}

// K4: per-batch inclusive cumsum
__global__ __launch_bounds__(1024) void cumsum_kernel(const int* __restrict__ dur,
                                                      int* __restrict__ cum) {
  __shared__ int s[P_];
  int b = blockIdx.x;
  int t = threadIdx.x;
  s[t] = dur[b * P_ + t];
  __syncthreads();
  for (int off = 1; off < P_; off <<= 1) {
    int v = (t >= off) ? s[t - off] : 0;
    __syncthreads();
    s[t] += v;
    __syncthreads();
  }
  cum[b * P_ + t] = s[t];
}

// ============================================================================
// K3: conv2 as single K-concat GEMM, 256x256 tile, BK=64, 8-phase schedule.
// Measured: ~109 µs (r5 probe) ≈ 1420 TF effective. Unchanged.
// ============================================================================
struct BTrue  { static constexpr bool v = true;  };
struct BFalse { static constexpr bool v = false; };

__global__ __launch_bounds__(512, 2) void conv2_gemm8_kernel(
    const unsigned short* __restrict__ A2h, const unsigned short* __restrict__ A2l,
    const unsigned short* __restrict__ Bh, const unsigned short* __restrict__ Bl,
    const float* __restrict__ bias2, float* __restrict__ out2) {
  __shared__ __align__(16) unsigned short sm[4][16384];  // Abuf0, Abuf1, Bbuf0, Bbuf1

  const int tid = threadIdx.x;
  const int wid = tid >> 6;
  const int lane = tid & 63;
  const int wm = wid >> 2, wn = wid & 3;
  const int fr = lane & 15, fq = lane >> 4;

  int bid = blockIdx.x;
  int wg = (bid & 7) * 32 + (bid >> 3);
  int m0 = (wg & 1) * 256;
  int n0 = (wg >> 1) * 256;
  int bb = n0 >> 10;
  int p0 = n0 & (P_ - 1);

  const unsigned short* Arow_h = A2h + (size_t)m0 * 1536;
  const unsigned short* Arow_l = A2l + (size_t)m0 * 1536;
  const size_t boff = ((size_t)bb * (P_ + 2) + p0) * 512;
  const unsigned short* Brow_h = Bh + boff;
  const unsigned short* Brow_l = Bl + boff;

  const int srow = tid >> 3;
  const int scol = (((tid & 7) ^ ((tid >> 3) & 7))) * 8;  // elems
  const int ldsw = wid * 512;                             // wave-uniform elems

  auto stageA = [&](int kt, int blk) {
    const unsigned short* base = (kt < 48) ? Arow_h : Arow_l;
    int kl = (kt % 24) * 64;
    const unsigned short* src = base + (size_t)(blk * 64 + srow) * 1536 + kl + scol;
    __builtin_amdgcn_global_load_lds(GLB(src), LDSP(&sm[kt & 1][blk * 4096 + ldsw]), 16, 0, 0);
  };
  auto stageB = [&](int kt, int blk) {
    const unsigned short* base = (kt >= 24 && kt < 48) ? Brow_l : Brow_h;
    int kl = (kt % 24) * 64;
    const unsigned short* src = base + (size_t)(blk * 64 + srow) * 512 + kl + scol;
    __builtin_amdgcn_global_load_lds(GLB(src), LDSP(&sm[2 + (kt & 1)][blk * 4096 + ldsw]), 16, 0, 0);
  };

  f32x4 acc[8][4] = {};

  const int rA0 = wm * 128 + fr;
  const int rB0 = wn * 64 + fr;
  const int cxor = fr & 7;

  auto rdA = [&](bf16x8 (&af)[4][2], int buf, int mh) {
#pragma unroll
    for (int m = 0; m < 4; ++m)
#pragma unroll
      for (int ks = 0; ks < 2; ++ks)
        af[m][ks] = *(const bf16x8*)&sm[buf][(rA0 + mh * 64 + m * 16) * 64 +
                                            ((ks * 4 + fq) ^ cxor) * 8];
  };
  auto rdB = [&](bf16x8 (&bv)[2][2], int buf, int nh) {
#pragma unroll
    for (int n = 0; n < 2; ++n)
#pragma unroll
      for (int ks = 0; ks < 2; ++ks)
        bv[n][ks] = *(const bf16x8*)&sm[2 + buf][(rB0 + nh * 32 + n * 16) * 64 +
                                                 ((ks * 4 + fq) ^ cxor) * 8];
  };

#define SYNC_HEAD()                                      \
  __builtin_amdgcn_sched_barrier(0);                     \
  __builtin_amdgcn_s_barrier();                          \
  asm volatile("s_waitcnt lgkmcnt(0)" ::: "memory");     \
  __builtin_amdgcn_sched_barrier(0);                     \
  __builtin_amdgcn_s_setprio(1)

#define SYNC_TAIL()                                      \
  __builtin_amdgcn_s_setprio(0);                         \
  __builtin_amdgcn_sched_barrier(0);                     \
  __builtin_amdgcn_s_barrier();                          \
  __builtin_amdgcn_sched_barrier(0)

#define MFMA_QUAD(mh, nh, AF, BF)                                              \
  _Pragma("unroll") for (int m = 0; m < 4; ++m)                                \
  _Pragma("unroll") for (int n = 0; n < 2; ++n)                                \
  _Pragma("unroll") for (int ks = 0; ks < 2; ++ks)                             \
    acc[(mh) * 4 + m][(nh) * 2 + n] = __builtin_amdgcn_mfma_f32_16x16x32_bf16( \
        AF[m][ks], BF[n][ks], acc[(mh) * 4 + m][(nh) * 2 + n], 0, 0, 0)

#pragma unroll
  for (int blk = 0; blk < 4; ++blk) { stageA(0, blk); stageB(0, blk); }
  stageA(1, 0); stageA(1, 2);
  asm volatile("s_waitcnt vmcnt(2)" ::: "memory");
  __builtin_amdgcn_sched_barrier(0);
  __builtin_amdgcn_s_barrier();
  __builtin_amdgcn_sched_barrier(0);

  int kt = 0;
  auto iter = [&](auto lasttag) {
    constexpr bool LAST = decltype(lasttag)::v;
    bf16x8 af[4][2], bv[2][2];
    rdA(af, 0, 0); rdB(bv, 0, 0);
    stageA(kt + 1, 1); stageA(kt + 1, 3); stageB(kt + 1, 0);
    SYNC_HEAD(); MFMA_QUAD(0, 0, af, bv); SYNC_TAIL();

    rdB(bv, 0, 1);
    stageB(kt + 1, 1); stageB(kt + 1, 2); stageB(kt + 1, 3);
    SYNC_HEAD(); MFMA_QUAD(0, 1, af, bv); SYNC_TAIL();

    rdA(af, 0, 1); rdB(bv, 0, 0);
    if constexpr (!LAST) { stageA(kt + 2, 0); stageA(kt + 2, 2); }
    SYNC_HEAD(); MFMA_QUAD(1, 0, af, bv); SYNC_TAIL();

    rdB(bv, 0, 1);
    __builtin_amdgcn_sched_barrier(0);
    __builtin_amdgcn_s_barrier();
    asm volatile("s_waitcnt lgkmcnt(0)" ::: "memory");
    __builtin_amdgcn_sched_barrier(0);
    __builtin_amdgcn_s_setprio(1);
    MFMA_QUAD(1, 1, af, bv);
    __builtin_amdgcn_s_setprio(0);
    __builtin_amdgcn_sched_barrier(0);
    if constexpr (LAST) asm volatile("s_waitcnt vmcnt(0)" ::: "memory");
    else                asm volatile("s_waitcnt vmcnt(2)" ::: "memory");
    __builtin_amdgcn_s_barrier();
    __builtin_amdgcn_sched_barrier(0);

    rdA(af, 1, 0); rdB(bv, 1, 0);
    if constexpr (!LAST) { stageA(kt + 2, 1); stageA(kt + 2, 3); stageB(kt + 2, 0); }
    SYNC_HEAD(); MFMA_QUAD(0, 0, af, bv); SYNC_TAIL();

    rdB(bv, 1, 1);
    if constexpr (!LAST) { stageB(kt + 2, 1); stageB(kt + 2, 2); stageB(kt + 2, 3); }
    SYNC_HEAD(); MFMA_QUAD(0, 1, af, bv); SYNC_TAIL();

    rdA(af, 1, 1); rdB(bv, 1, 0);
    if constexpr (!LAST) { stageA(kt + 3, 0); stageA(kt + 3, 2); }
    SYNC_HEAD(); MFMA_QUAD(1, 0, af, bv); SYNC_TAIL();

    rdB(bv, 1, 1);
    __builtin_amdgcn_sched_barrier(0);
    __builtin_amdgcn_s_barrier();
    asm volatile("s_waitcnt lgkmcnt(0)" ::: "memory");
    __builtin_amdgcn_sched_barrier(0);
    __builtin_amdgcn_s_setprio(1);
    MFMA_QUAD(1, 1, af, bv);
    __builtin_amdgcn_s_setprio(0);
    __builtin_amdgcn_sched_barrier(0);
    if constexpr (!LAST) {
      asm volatile("s_waitcnt vmcnt(2)" ::: "memory");
      __builtin_amdgcn_s_barrier();
      __builtin_amdgcn_sched_barrier(0);
    }
    kt += 2;
  };

  for (int i = 0; i < 35; ++i) iter(BFalse{});
  iter(BTrue{});

#pragma unroll
  for (int ai = 0; ai < 8; ++ai) {
    int row = m0 + wm * 128 + (ai >> 2) * 64 + (ai & 3) * 16 + fq * 4;
#pragma unroll
    for (int bj = 0; bj < 4; ++bj) {
      int col = n0 + wn * 64 + (bj >> 1) * 32 + (bj & 1) * 16 + fr;
      int bb2 = col >> 10;
      int p = col & (P_ - 1);
#pragma unroll
      for (int r = 0; r < 4; ++r) {
        float v = acc[ai][bj][r] + bias2[row + r];
        out2[((size_t)bb2 * H_ + row + r) * P_ + p] = fmaxf(v, 0.f);
      }
    }
  }
#undef SYNC_HEAD
#undef SYNC_TAIL
#undef MFMA_QUAD
}

// K5: upsample. 2-D grid over (t-quad, h-block, batch); 4 t per thread,
// one float4 store per h-row (1KB/wave/instr). Plain stores (nontemporal
// regressed in r6). Fast path when all 4 frames share one phoneme.
__global__ __launch_bounds__(256) void upsample_kernel(const float* __restrict__ out2,
                                                       const int* __restrict__ cum,
                                                       float* __restrict__ out, int T) {
  __shared__ int sc[P_];
  int b = blockIdx.z;
  int h0 = blockIdx.y * 64;
  int tid = threadIdx.x;
  for (int i = tid; i < P_; i += 256) sc[i] = cum[b * P_ + i];
  __syncthreads();
  int t0 = (blockIdx.x * 256 + tid) * 4;
  if (t0 >= T) return;
  int tot = sc[P_ - 1];
  int idx[4];
  bool val[4];
#pragma unroll
  for (int u = 0; u < 4; ++u) {
    int t = t0 + u;
    val[u] = (t < tot);
    int lo = 0, hi = P_;
    while (lo < hi) {
      int mid = (lo + hi) >> 1;
      if (sc[mid] <= t) lo = mid + 1; else hi = mid;
    }
    idx[u] = min(lo, P_ - 1);
  }
  const float* src = out2 + ((size_t)b * H_ + h0) * P_;
  float* dst = out + ((size_t)b * H_ + h0) * T;
  bool fullvec = (t0 + 4 <= T) && ((T & 3) == 0);
  if (fullvec) {
    if (val[3] && idx[0] == idx[3]) {
      // all 4 frames from the same phoneme: 1 load, splat
#pragma unroll 8
      for (int h = 0; h < 64; ++h) {
        float v = src[(size_t)h * P_ + idx[0]];
        float4 o = {v, v, v, v};
        *(float4*)&dst[(size_t)h * T + t0] = o;
      }
    } else {
#pragma unroll 4
      for (int h = 0; h < 64; ++h) {
        const float* sr = src + (size_t)h * P_;
        float4 o;
        o.x = val[0] ? sr[idx[0]] : 0.f;
        o.y = val[1] ? sr[idx[1]] : 0.f;
        o.z = val[2] ? sr[idx[2]] : 0.f;
        o.w = val[3] ? sr[idx[3]] : 0.f;
        *(float4*)&dst[(size_t)h * T + t0] = o;
      }
    }
  } else {
    for (int h = 0; h < 64; ++h) {
      const float* sr = src + (size_t)h * P_;
      float* dr = dst + (size_t)h * T;
#pragma unroll
      for (int u = 0; u < 4; ++u) {
        int t = t0 + u;
        if (t < T) dr[t] = val[u] ? sr[idx[u]] : 0.f;
      }
    }
  }
}

static inline size_t align256(size_t x) { return (x + 255) & ~(size_t)255; }

extern "C" void kernel_launch(void* const* d_in, const int* in_sizes, int n_in,
                              void* d_out, int out_size, void* d_ws, size_t ws_size,
                              hipStream_t stream) {
  const int*   ids = (const int*)d_in[0];
  const int*   dur = (const int*)d_in[1];
  const float* emb = (const float*)d_in[2];
  const float* w1  = (const float*)d_in[3];
  const float* b1  = (const float*)d_in[4];
  const float* g1  = (const float*)d_in[5];
  const float* be1 = (const float*)d_in[6];
  const float* mn1 = (const float*)d_in[7];
  const float* vr1 = (const float*)d_in[8];
  const float* w2  = (const float*)d_in[9];
  const float* b2  = (const float*)d_in[10];
  const float* g2  = (const float*)d_in[11];
  const float* be2 = (const float*)d_in[12];
  const float* mn2 = (const float*)d_in[13];
  const float* vr2 = (const float*)d_in[14];
  float* out = (float*)d_out;

  int T = out_size / (B_ * H_);

  char* ws = (char*)d_ws;
  size_t off = 0;
  auto carve = [&](size_t bytes) { void* p = ws + off; off = align256(off + bytes); return p; };
  float* G              = (float*)carve((size_t)3 * V_ * H_ * 4);
  float* w1T            = (float*)carve((size_t)3 * E_ * H_ * 4);
  float* bias1          = (float*)carve(H_ * 4);
  float* bias2          = (float*)carve(H_ * 4);
  unsigned short* A2h   = (unsigned short*)carve((size_t)H_ * 3 * C_ * 2);
  unsigned short* A2l   = (unsigned short*)carve((size_t)H_ * 3 * C_ * 2);
  unsigned short* Bhv   = (unsigned short*)carve((size_t)B_ * (P_ + 2) * C_ * 2);
  unsigned short* Blv   = (unsigned short*)carve((size_t)B_ * (P_ + 2) * C_ * 2);
  float* out2           = (float*)carve((size_t)B_ * H_ * P_ * 4);
  int* cum              = (int*)carve((size_t)B_ * P_ * 4);

  w1t_kernel<<<dim3(H_ / 64, (3 * E_) / 64), 256, 0, stream>>>(w1, w1T);
  a2_kernel<<<H_, 256, 0, stream>>>(w2, b1, g1, be1, mn1, vr1, b2, g2, be2, mn2, vr2,
                                    bias1, bias2, A2h, A2l);
  g_kernel<<<dim3(V_, H_ / 64), 64, 0, stream>>>(emb, w1T, g1, vr1, G);
  embed_conv1_kernel<<<B_ * (P_ + 2), 256, 0, stream>>>(ids, G, bias1, Bhv, Blv);
  cumsum_kernel<<<B_, P_, 0, stream>>>(dur, cum);
  conv2_gemm8_kernel<<<256, 512, 0, stream>>>(A2h, A2l, Bhv, Blv, bias2, out2);
  upsample_kernel<<<dim3((T + 1023) / 1024, H_ / 64, B_), 256, 0, stream>>>(out2, cum, out, T);
}

// Round 8
// 619.826 us; speedup vs baseline: 1.1139x; 1.1139x over previous
//
#include <hip/hip_runtime.h>

#define B_ 32
#define P_ 1024
#define V_ 100
#define E_ 512
#define H_ 512
#define C_ 512
#define EPS_ 1e-5f

typedef float f32x4 __attribute__((ext_vector_type(4)));
typedef short bf16x8 __attribute__((ext_vector_type(8)));

#define GLB(p) ((const __attribute__((address_space(1))) unsigned int*)(p))
#define LDSP(p) ((__attribute__((address_space(3))) unsigned int*)(p))

__device__ __forceinline__ unsigned short f2bf(float f) {
  unsigned int u = __float_as_uint(f);
  u += 0x7fffu + ((u >> 16) & 1u);
  return (unsigned short)(u >> 16);
}
__device__ __forceinline__ float bf2f(unsigned short s) {
  return __uint_as_float(((unsigned int)s) << 16);
}

// K0: transpose w1 [H][E*3] -> w1T [E*3][H]
__global__ __launch_bounds__(256) void w1t_kernel(const float* __restrict__ w1,
                                                  float* __restrict__ w1T) {
  __shared__ float tile[64][65];
  int h0 = blockIdx.x * 64;
  int e0 = blockIdx.y * 64;
  int t = threadIdx.x;
  int c = t & 63, r4 = t >> 6;
#pragma unroll
  for (int r = 0; r < 64; r += 4)
    tile[r + r4][c] = w1[(size_t)(h0 + r + r4) * 1536 + e0 + c];
  __syncthreads();
#pragma unroll
  for (int r = 0; r < 64; r += 4)
    w1T[(size_t)(e0 + r + r4) * 512 + h0 + c] = tile[c][r + r4];
}

// K1: G[k][v][h] = scale1[h] * sum_e w1T[3e+k][h] * emb[v,e]
// known-good r4 config: grid (V, H/64), 64 threads.
__global__ __launch_bounds__(64) void g_kernel(const float* __restrict__ emb,
                                               const float* __restrict__ w1T,
                                               const float* __restrict__ g1,
                                               const float* __restrict__ vr1,
                                               float* __restrict__ G) {
  __shared__ float se[E_];
  int v = blockIdx.x;
  int h = blockIdx.y * 64 + threadIdx.x;
  for (int i = threadIdx.x; i < E_; i += 64) se[i] = emb[(size_t)v * E_ + i];
  __syncthreads();
  float a0 = 0.f, a1 = 0.f, a2 = 0.f;
#pragma unroll 4
  for (int e = 0; e < E_; ++e) {
    float x = se[e];
    const float* wp = w1T + (size_t)(3 * e) * H_ + h;
    a0 = fmaf(wp[0], x, a0);
    a1 = fmaf(wp[H_], x, a1);
    a2 = fmaf(wp[2 * H_], x, a2);
  }
  float sc = g1[h] * rsqrtf(vr1[h] + EPS_);
  G[((size_t)0 * V_ + v) * H_ + h] = a0 * sc;
  G[((size_t)1 * V_ + v) * H_ + h] = a1 * sc;
  G[((size_t)2 * V_ + v) * H_ + h] = a2 * sc;
}

// K1b: repack/split w2 -> A2 (H x 1536, j = k*C + c), fold scale2; biases.
__global__ __launch_bounds__(256) void a2_kernel(
    const float* __restrict__ w2, const float* __restrict__ b1,
    const float* __restrict__ g1, const float* __restrict__ be1,
    const float* __restrict__ mn1, const float* __restrict__ vr1,
    const float* __restrict__ b2, const float* __restrict__ g2,
    const float* __restrict__ be2, const float* __restrict__ mn2,
    const float* __restrict__ vr2, float* __restrict__ bias1,
    float* __restrict__ bias2, unsigned short* __restrict__ A2h,
    unsigned short* __restrict__ A2l) {
  int h = blockIdx.x;
  int tid = threadIdx.x;
  float sc1 = g1[h] * rsqrtf(vr1[h] + EPS_);
  float sc2 = g2[h] * rsqrtf(vr2[h] + EPS_);
  if (tid == 0) {
    bias1[h] = b1[h] * sc1 + be1[h] - mn1[h] * sc1;
    bias2[h] = b2[h] * sc2 + be2[h] - mn2[h] * sc2;
  }
  for (int j = tid; j < 3 * C_; j += 256) {
    int k = j >> 9;
    int c = j & (C_ - 1);
    float val = w2[((size_t)h * C_ + c) * 3 + k] * sc2;
    unsigned short hi = f2bf(val);
    A2h[(size_t)h * (3 * C_) + j] = hi;
    A2l[(size_t)h * (3 * C_) + j] = f2bf(val - bf2f(hi));
  }
}

// K2: h1T[b][r][c] padded rows; 2 channels/thread, packed stores
__global__ __launch_bounds__(256) void embed_conv1_kernel(
    const int* __restrict__ ids, const float* __restrict__ G,
    const float* __restrict__ bias1, unsigned short* __restrict__ Bh,
    unsigned short* __restrict__ Bl) {
  int r = blockIdx.x % (P_ + 2);
  int b = blockIdx.x / (P_ + 2);
  int t = threadIdx.x;
  size_t outbase = ((size_t)b * (P_ + 2) + r) * C_;
  unsigned int* BhU = (unsigned int*)(Bh + outbase);
  unsigned int* BlU = (unsigned int*)(Bl + outbase);
  if (r == 0 || r == P_ + 1) {
    BhU[t] = 0u;
    BlU[t] = 0u;
    return;
  }
  int p = r - 1;
  int v0 = (p >= 1) ? ids[b * P_ + p - 1] : -1;
  int v1 = ids[b * P_ + p];
  int v2 = (p + 1 < P_) ? ids[b * P_ + p + 1] : -1;
  const float2* G0 = (v0 >= 0) ? (const float2*)(G + ((size_t)0 * V_ + v0) * H_) : nullptr;
  const float2* G1 = (const float2*)(G + ((size_t)1 * V_ + v1) * H_);
  const float2* G2 = (v2 >= 0) ? (const float2*)(G + ((size_t)2 * V_ + v2) * H_) : nullptr;
  const float2* bi = (const float2*)bias1;

  float2 s = bi[t];
  float2 gm = G1[t];
  s.x += gm.x;
  s.y += gm.y;
  if (G0) { float2 g0 = G0[t]; s.x += g0.x; s.y += g0.y; }
  if (G2) { float2 g2v = G2[t]; s.x += g2v.x; s.y += g2v.y; }
  s.x = fmaxf(s.x, 0.f);
  s.y = fmaxf(s.y, 0.f);
  unsigned short h0 = f2bf(s.x), h1 = f2bf(s.y);
  unsigned short l0 = f2bf(s.x - bf2f(h0)), l1 = f2bf(s.y - bf2f(h1));
  BhU[t] = (unsigned int)h0 | ((unsigned int)h1 << 16);
  BlU[t] = (unsigned int)l0 | ((unsigned int)l1 << 16);
}

// K4: per-batch inclusive cumsum
__global__ __launch_bounds__(1024) void cumsum_kernel(const int* __restrict__ dur,
                                                      int* __restrict__ cum) {
  __shared__ int s[P_];
  int b = blockIdx.x;
  int t = threadIdx.x;
  s[t] = dur[b * P_ + t];
  __syncthreads();
  for (int off = 1; off < P_; off <<= 1) {
    int v = (t >= off) ? s[t - off] : 0;
    __syncthreads();
    s[t] += v;
    __syncthreads();
  }
  cum[b * P_ + t] = s[t];
}

// ============================================================================
// K3: conv2 K-concat GEMM, 256x256 tile, BK=64, 8-phase (measured ~109 µs,
// 1420 TF). This round: epilogue stores out2 as BF16 (halves write bytes,
// makes out2 L3-resident for upsample).
// ============================================================================
struct BTrue  { static constexpr bool v = true;  };
struct BFalse { static constexpr bool v = false; };

__global__ __launch_bounds__(512, 2) void conv2_gemm8_kernel(
    const unsigned short* __restrict__ A2h, const unsigned short* __restrict__ A2l,
    const unsigned short* __restrict__ Bh, const unsigned short* __restrict__ Bl,
    const float* __restrict__ bias2, unsigned short* __restrict__ out2b) {
  __shared__ __align__(16) unsigned short sm[4][16384];  // Abuf0, Abuf1, Bbuf0, Bbuf1

  const int tid = threadIdx.x;
  const int wid = tid >> 6;
  const int lane = tid & 63;
  const int wm = wid >> 2, wn = wid & 3;
  const int fr = lane & 15, fq = lane >> 4;

  int bid = blockIdx.x;
  int wg = (bid & 7) * 32 + (bid >> 3);
  int m0 = (wg & 1) * 256;
  int n0 = (wg >> 1) * 256;
  int bb = n0 >> 10;
  int p0 = n0 & (P_ - 1);

  const unsigned short* Arow_h = A2h + (size_t)m0 * 1536;
  const unsigned short* Arow_l = A2l + (size_t)m0 * 1536;
  const size_t boff = ((size_t)bb * (P_ + 2) + p0) * 512;
  const unsigned short* Brow_h = Bh + boff;
  const unsigned short* Brow_l = Bl + boff;

  const int srow = tid >> 3;
  const int scol = (((tid & 7) ^ ((tid >> 3) & 7))) * 8;  // elems
  const int ldsw = wid * 512;                             // wave-uniform elems

  auto stageA = [&](int kt, int blk) {
    const unsigned short* base = (kt < 48) ? Arow_h : Arow_l;
    int kl = (kt % 24) * 64;
    const unsigned short* src = base + (size_t)(blk * 64 + srow) * 1536 + kl + scol;
    __builtin_amdgcn_global_load_lds(GLB(src), LDSP(&sm[kt & 1][blk * 4096 + ldsw]), 16, 0, 0);
  };
  auto stageB = [&](int kt, int blk) {
    const unsigned short* base = (kt >= 24 && kt < 48) ? Brow_l : Brow_h;
    int kl = (kt % 24) * 64;
    const unsigned short* src = base + (size_t)(blk * 64 + srow) * 512 + kl + scol;
    __builtin_amdgcn_global_load_lds(GLB(src), LDSP(&sm[2 + (kt & 1)][blk * 4096 + ldsw]), 16, 0, 0);
  };

  f32x4 acc[8][4] = {};

  const int rA0 = wm * 128 + fr;
  const int rB0 = wn * 64 + fr;
  const int cxor = fr & 7;

  auto rdA = [&](bf16x8 (&af)[4][2], int buf, int mh) {
#pragma unroll
    for (int m = 0; m < 4; ++m)
#pragma unroll
      for (int ks = 0; ks < 2; ++ks)
        af[m][ks] = *(const bf16x8*)&sm[buf][(rA0 + mh * 64 + m * 16) * 64 +
                                            ((ks * 4 + fq) ^ cxor) * 8];
  };
  auto rdB = [&](bf16x8 (&bv)[2][2], int buf, int nh) {
#pragma unroll
    for (int n = 0; n < 2; ++n)
#pragma unroll
      for (int ks = 0; ks < 2; ++ks)
        bv[n][ks] = *(const bf16x8*)&sm[2 + buf][(rB0 + nh * 32 + n * 16) * 64 +
                                                 ((ks * 4 + fq) ^ cxor) * 8];
  };

#define SYNC_HEAD()                                      \
  __builtin_amdgcn_sched_barrier(0);                     \
  __builtin_amdgcn_s_barrier();                          \
  asm volatile("s_waitcnt lgkmcnt(0)" ::: "memory");     \
  __builtin_amdgcn_sched_barrier(0);                     \
  __builtin_amdgcn_s_setprio(1)

#define SYNC_TAIL()                                      \
  __builtin_amdgcn_s_setprio(0);                         \
  __builtin_amdgcn_sched_barrier(0);                     \
  __builtin_amdgcn_s_barrier();                          \
  __builtin_amdgcn_sched_barrier(0)

#define MFMA_QUAD(mh, nh, AF, BF)                                              \
  _Pragma("unroll") for (int m = 0; m < 4; ++m)                                \
  _Pragma("unroll") for (int n = 0; n < 2; ++n)                                \
  _Pragma("unroll") for (int ks = 0; ks < 2; ++ks)                             \
    acc[(mh) * 4 + m][(nh) * 2 + n] = __builtin_amdgcn_mfma_f32_16x16x32_bf16( \
        AF[m][ks], BF[n][ks], acc[(mh) * 4 + m][(nh) * 2 + n], 0, 0, 0)

#pragma unroll
  for (int blk = 0; blk < 4; ++blk) { stageA(0, blk); stageB(0, blk); }
  stageA(1, 0); stageA(1, 2);
  asm volatile("s_waitcnt vmcnt(2)" ::: "memory");
  __builtin_amdgcn_sched_barrier(0);
  __builtin_amdgcn_s_barrier();
  __builtin_amdgcn_sched_barrier(0);

  int kt = 0;
  auto iter = [&](auto lasttag) {
    constexpr bool LAST = decltype(lasttag)::v;
    bf16x8 af[4][2], bv[2][2];
    rdA(af, 0, 0); rdB(bv, 0, 0);
    stageA(kt + 1, 1); stageA(kt + 1, 3); stageB(kt + 1, 0);
    SYNC_HEAD(); MFMA_QUAD(0, 0, af, bv); SYNC_TAIL();

    rdB(bv, 0, 1);
    stageB(kt + 1, 1); stageB(kt + 1, 2); stageB(kt + 1, 3);
    SYNC_HEAD(); MFMA_QUAD(0, 1, af, bv); SYNC_TAIL();

    rdA(af, 0, 1); rdB(bv, 0, 0);
    if constexpr (!LAST) { stageA(kt + 2, 0); stageA(kt + 2, 2); }
    SYNC_HEAD(); MFMA_QUAD(1, 0, af, bv); SYNC_TAIL();

    rdB(bv, 0, 1);
    __builtin_amdgcn_sched_barrier(0);
    __builtin_amdgcn_s_barrier();
    asm volatile("s_waitcnt lgkmcnt(0)" ::: "memory");
    __builtin_amdgcn_sched_barrier(0);
    __builtin_amdgcn_s_setprio(1);
    MFMA_QUAD(1, 1, af, bv);
    __builtin_amdgcn_s_setprio(0);
    __builtin_amdgcn_sched_barrier(0);
    if constexpr (LAST) asm volatile("s_waitcnt vmcnt(0)" ::: "memory");
    else                asm volatile("s_waitcnt vmcnt(2)" ::: "memory");
    __builtin_amdgcn_s_barrier();
    __builtin_amdgcn_sched_barrier(0);

    rdA(af, 1, 0); rdB(bv, 1, 0);
    if constexpr (!LAST) { stageA(kt + 2, 1); stageA(kt + 2, 3); stageB(kt + 2, 0); }
    SYNC_HEAD(); MFMA_QUAD(0, 0, af, bv); SYNC_TAIL();

    rdB(bv, 1, 1);
    if constexpr (!LAST) { stageB(kt + 2, 1); stageB(kt + 2, 2); stageB(kt + 2, 3); }
    SYNC_HEAD(); MFMA_QUAD(0, 1, af, bv); SYNC_TAIL();

    rdA(af, 1, 1); rdB(bv, 1, 0);
    if constexpr (!LAST) { stageA(kt + 3, 0); stageA(kt + 3, 2); }
    SYNC_HEAD(); MFMA_QUAD(1, 0, af, bv); SYNC_TAIL();

    rdB(bv, 1, 1);
    __builtin_amdgcn_sched_barrier(0);
    __builtin_amdgcn_s_barrier();
    asm volatile("s_waitcnt lgkmcnt(0)" ::: "memory");
    __builtin_amdgcn_sched_barrier(0);
    __builtin_amdgcn_s_setprio(1);
    MFMA_QUAD(1, 1, af, bv);
    __builtin_amdgcn_s_setprio(0);
    __builtin_amdgcn_sched_barrier(0);
    if constexpr (!LAST) {
      asm volatile("s_waitcnt vmcnt(2)" ::: "memory");
      __builtin_amdgcn_s_barrier();
      __builtin_amdgcn_sched_barrier(0);
    }
    kt += 2;
  };

  for (int i = 0; i < 35; ++i) iter(BFalse{});
  iter(BTrue{});

  // Epilogue: bf16 stores (half the write bytes; out2 L3-resident for K5)
#pragma unroll
  for (int ai = 0; ai < 8; ++ai) {
    int row = m0 + wm * 128 + (ai >> 2) * 64 + (ai & 3) * 16 + fq * 4;
#pragma unroll
    for (int bj = 0; bj < 4; ++bj) {
      int col = n0 + wn * 64 + (bj >> 1) * 32 + (bj & 1) * 16 + fr;
      int bb2 = col >> 10;
      int p = col & (P_ - 1);
#pragma unroll
      for (int r = 0; r < 4; ++r) {
        float v = acc[ai][bj][r] + bias2[row + r];
        out2b[((size_t)bb2 * H_ + row + r) * P_ + p] = f2bf(fmaxf(v, 0.f));
      }
    }
  }
#undef SYNC_HEAD
#undef SYNC_TAIL
#undef MFMA_QUAD
}

// K5: upsample — r4's known-good shape (1 frame/thread, 64 h rows, 5120
// blocks), now reading bf16 out2 (L3-resident) and writing f32.
__global__ __launch_bounds__(256) void upsample_kernel(const unsigned short* __restrict__ out2b,
                                                       const int* __restrict__ cum,
                                                       float* __restrict__ out, int T) {
  __shared__ int sc[P_];
  int b = blockIdx.z;
  int h0 = blockIdx.y * 64;
  int tid = threadIdx.x;
  for (int i = tid; i < P_; i += 256) sc[i] = cum[b * P_ + i];
  __syncthreads();
  int t = blockIdx.x * 256 + tid;
  if (t >= T) return;
  int tot = sc[P_ - 1];
  bool valid = (t < tot);
  int lo = 0, hi = P_;
  while (lo < hi) {
    int mid = (lo + hi) >> 1;
    if (sc[mid] <= t) lo = mid + 1; else hi = mid;
  }
  int idx = min(lo, P_ - 1);
  const unsigned short* src = out2b + ((size_t)b * H_ + h0) * P_ + idx;
  float* dst = out + ((size_t)b * H_ + h0) * T + t;
  if (valid) {
#pragma unroll 8
    for (int h = 0; h < 64; ++h) dst[(size_t)h * T] = bf2f(src[(size_t)h * P_]);
  } else {
#pragma unroll 8
    for (int h = 0; h < 64; ++h) dst[(size_t)h * T] = 0.f;
  }
}

static inline size_t align256(size_t x) { return (x + 255) & ~(size_t)255; }

extern "C" void kernel_launch(void* const* d_in, const int* in_sizes, int n_in,
                              void* d_out, int out_size, void* d_ws, size_t ws_size,
                              hipStream_t stream) {
  const int*   ids = (const int*)d_in[0];
  const int*   dur = (const int*)d_in[1];
  const float* emb = (const float*)d_in[2];
  const float* w1  = (const float*)d_in[3];
  const float* b1  = (const float*)d_in[4];
  const float* g1  = (const float*)d_in[5];
  const float* be1 = (const float*)d_in[6];
  const float* mn1 = (const float*)d_in[7];
  const float* vr1 = (const float*)d_in[8];
  const float* w2  = (const float*)d_in[9];
  const float* b2  = (const float*)d_in[10];
  const float* g2  = (const float*)d_in[11];
  const float* be2 = (const float*)d_in[12];
  const float* mn2 = (const float*)d_in[13];
  const float* vr2 = (const float*)d_in[14];
  float* out = (float*)d_out;

  int T = out_size / (B_ * H_);

  char* ws = (char*)d_ws;
  size_t off = 0;
  auto carve = [&](size_t bytes) { void* p = ws + off; off = align256(off + bytes); return p; };
  float* G              = (float*)carve((size_t)3 * V_ * H_ * 4);
  float* w1T            = (float*)carve((size_t)3 * E_ * H_ * 4);
  float* bias1          = (float*)carve(H_ * 4);
  float* bias2          = (float*)carve(H_ * 4);
  unsigned short* A2h   = (unsigned short*)carve((size_t)H_ * 3 * C_ * 2);
  unsigned short* A2l   = (unsigned short*)carve((size_t)H_ * 3 * C_ * 2);
  unsigned short* Bhv   = (unsigned short*)carve((size_t)B_ * (P_ + 2) * C_ * 2);
  unsigned short* Blv   = (unsigned short*)carve((size_t)B_ * (P_ + 2) * C_ * 2);
  unsigned short* out2b = (unsigned short*)carve((size_t)B_ * H_ * P_ * 2);
  int* cum              = (int*)carve((size_t)B_ * P_ * 4);

  w1t_kernel<<<dim3(H_ / 64, (3 * E_) / 64), 256, 0, stream>>>(w1, w1T);
  a2_kernel<<<H_, 256, 0, stream>>>(w2, b1, g1, be1, mn1, vr1, b2, g2, be2, mn2, vr2,
                                    bias1, bias2, A2h, A2l);
  g_kernel<<<dim3(V_, H_ / 64), 64, 0, stream>>>(emb, w1T, g1, vr1, G);
  embed_conv1_kernel<<<B_ * (P_ + 2), 256, 0, stream>>>(ids, G, bias1, Bhv, Blv);
  cumsum_kernel<<<B_, P_, 0, stream>>>(dur, cum);
  conv2_gemm8_kernel<<<256, 512, 0, stream>>>(A2h, A2l, Bhv, Blv, bias2, out2b);
  upsample_kernel<<<dim3((T + 255) / 256, H_ / 64, B_), 256, 0, stream>>>(out2b, cum, out, T);
}